// Round 14
// baseline (7193.669 us; speedup 1.0000x reference)
//
#include <hip/hip_runtime.h>
#include <cstddef>

#define TSTEPS 4096
#define INLEN  1910
#define NROW   40
#define NCOL   50
#define NCELL  2000
#define NTHR   512
#define CHUNK  16          // producer->consumer flag amortization

// padded field dims for the pre-pass
#define PPH 42
#define PPW 52

typedef float f2 __attribute__((ext_vector_type(2)));
typedef float f4 __attribute__((ext_vector_type(4)));
typedef long long i64;

#define L2E  1.4426950408889634f
#define SGK  (-2.f * L2E)          // scale applied to tanh() args (and c-state)

// d_ws layout (pipe path): [0,8000) feat | [8192,8704) flags | [16384, +zx) zx/U-ring
#define FLAGS_OFF 8192
#define ZX_OFF    16384

// ---------- math helpers ----------
__device__ __forceinline__ float fastrcp(float x)  { return __builtin_amdgcn_rcpf(x); }
__device__ __forceinline__ float fastexp2(float x) { return __builtin_amdgcn_exp2f(x); }
// legacy (fallback kernel + fc)
__device__ __forceinline__ float sigm(float x)   { return fastrcp(1.0f + __expf(-x)); }
__device__ __forceinline__ float tanh_f(float x) { return 2.0f * fastrcp(1.0f + __expf(-2.0f * x)) - 1.0f; }

// LDS-only barrier: orders LDS ops but lets global loads/stores stay in flight
__device__ __forceinline__ void ldsbar() {
    asm volatile("s_waitcnt lgkmcnt(0)\n\ts_barrier" ::: "memory");
}

// ---------- DPP full-wave lane shifts (zero fill at wave ends) ----------
__device__ __forceinline__ float lane_left(float x) {   // lane i <- lane i-1; lane0 -> 0
    int r = __builtin_amdgcn_update_dpp(0, __builtin_bit_cast(int, x),
                                        0x138 /*WAVE_SHR1*/, 0xF, 0xF, true);
    return __builtin_bit_cast(float, r);
}
__device__ __forceinline__ float lane_right(float x) {  // lane i <- lane i+1; lane63 -> 0
    int r = __builtin_amdgcn_update_dpp(0, __builtin_bit_cast(int, x),
                                        0x130 /*WAVE_SHL1*/, 0xF, 0xF, true);
    return __builtin_bit_cast(float, r);
}

// packed fp32 FMA; VOP3P requires 64-bit-pair operands, so the value goes in
// an f2 whose LO half carries the data (op_sel_hi[src1]=0 broadcasts lo).
__device__ __forceinline__ void pkfma_v(f2 &acc, f2 w, f2 vlo) {
    asm("v_pk_fma_f32 %0, %1, %2, %0 op_sel_hi:[1,0,1]" : "+v"(acc) : "v"(w), "v"(vlo));
}
__device__ __forceinline__ void pkfma_s(f2 &acc, i64 w, f2 vlo) {
    asm("v_pk_fma_f32 %0, %1, %2, %0 op_sel_hi:[1,0,1]" : "+v"(acc) : "s"(w), "v"(vlo));
}
__device__ __forceinline__ f2 pkfma3_s(i64 w, f2 vlo, f2 B) {
    f2 d;
    asm("v_pk_fma_f32 %0, %1, %2, %3 op_sel_hi:[1,0,1]" : "=v"(d) : "s"(w), "v"(vlo), "v"(B));
    return d;
}

// pack two uniform floats into an SGPR pair
__device__ __forceinline__ i64 mk_sw(float lo, float hi) {
    int l = __builtin_amdgcn_readfirstlane(__builtin_bit_cast(int, lo));
    int h = __builtin_amdgcn_readfirstlane(__builtin_bit_cast(int, hi));
    return (i64)((unsigned long long)(unsigned)l | ((unsigned long long)(unsigned)h << 32));
}

// 3x3 conv over 7 stencil rows -> 5 output rows; VGPR weights (round-11 form)
__device__ __forceinline__ void conv5_v(const float (&e)[7], const f2 (&Wa)[9], const f2 (&Wb)[9],
                                        f2 (&aA)[5], f2 (&aB)[5]) {
#pragma unroll
    for (int rr = 0; rr < 7; ++rr) {
        f2 Lv, Ev, Rv;                 // hi halves unused (op_sel broadcast reads lo)
        Lv.x = lane_left(e[rr]);
        Ev.x = e[rr];
        Rv.x = lane_right(e[rr]);
        const int ilo = (rr - 2 > 0) ? (rr - 2) : 0;
        const int ihi = (rr < 4) ? rr : 4;
#pragma unroll
        for (int i = ilo; i <= ihi; ++i) {
            const int k = (rr - i) * 3;
            pkfma_v(aA[i], Wa[k],     Lv);
            pkfma_v(aA[i], Wa[k + 1], Ev);
            pkfma_v(aA[i], Wa[k + 2], Rv);
            pkfma_v(aB[i], Wb[k],     Lv);
            pkfma_v(aB[i], Wb[k + 1], Ev);
            pkfma_v(aB[i], Wb[k + 2], Rv);
        }
    }
}

// SGPR-weight conv; INIT=true initializes acc i at its first tap with bias B
template<bool INIT>
__device__ __forceinline__ void conv5_s(const float (&e)[7], const i64 (&Wa)[9], const i64 (&Wb)[9],
                                        f2 (&aA)[5], f2 (&aB)[5], f2 Ba, f2 Bb) {
#pragma unroll
    for (int rr = 0; rr < 7; ++rr) {
        f2 Lv, Ev, Rv;
        Lv.x = lane_left(e[rr]);
        Ev.x = e[rr];
        Rv.x = lane_right(e[rr]);
        const int ilo = (rr - 2 > 0) ? (rr - 2) : 0;
        const int ihi = (rr < 4) ? rr : 4;
#pragma unroll
        for (int i = ilo; i <= ihi; ++i) {
            const int k = (rr - i) * 3;
            if (INIT && rr == i) {     // first touch of acc i
                aA[i] = pkfma3_s(Wa[k], Lv, Ba);
                aB[i] = pkfma3_s(Wb[k], Lv, Bb);
            } else {
                pkfma_s(aA[i], Wa[k], Lv);
                pkfma_s(aB[i], Wb[k], Lv);
            }
            pkfma_s(aA[i], Wa[k + 1], Ev);
            pkfma_s(aA[i], Wa[k + 2], Rv);
            pkfma_s(aB[i], Wb[k + 1], Ev);
            pkfma_s(aB[i], Wb[k + 2], Rv);
        }
    }
}

// Fused LSTM gate update, 7 transcendentals (5 exp2 + 2 rcp).
__device__ __forceinline__ float gates_update(f2 zA, f2 zB, float &cs, float maskf, float sgkv) {
    const float ea = fastexp2(zA.x);           // e^-i
    const float eb = fastexp2(zA.y);           // e^-f
    const float ec = fastexp2(zB.x);           // e^-o
    const float ed = fastexp2(zB.y);           // e^-2g
    const float Q  = 1.f + eb;
    const float P1 = (1.f + ea) * (1.f + ed);
    const float r1 = fastrcp(Q * P1);
    const float sf = P1 * r1;                  // sigmoid(f)
    const float nm = ed * (2.f * L2E) + sgkv;  // SGK*(1-ed)
    const float sitgS = Q * nm * r1;           // SGK * sigmoid(i)*tanh(g)
    cs = sf * cs + sitgS;                      // SGK * c_new
    const float ee = fastexp2(cs);             // e^-2c
    const float r2 = fastrcp((1.f + ec) * (1.f + ee));
    return (1.f - ee) * r2 * maskf;            // sigmoid(o)*tanh(c)
}

// ============================================================================
// Pre-pass: zx[t][cell] = f4{i,f,o,g}, pre-scaled; zeroes flags.
// ============================================================================
__global__ __launch_bounds__(256) void zx_prepass4(const float* __restrict__ s,
                                                   const float* __restrict__ w0,
                                                   const float* __restrict__ b0,
                                                   float* __restrict__ zx,
                                                   int* __restrict__ flags) {
    __shared__ float xf[PPH * PPW];
    const int t = blockIdx.x;
    const int tid = threadIdx.x;
    if (t == 0 && tid < 8) flags[tid * 16] = 0;
    for (int i = tid; i < PPH * PPW; i += 256) xf[i] = 0.f;
    __syncthreads();
    const float* __restrict__ xs = s + (size_t)t * INLEN;
    for (int j = tid; j < INLEN; j += 256) {
        const int r = j / NCOL, c = j % NCOL;
        xf[(r + 1) * PPW + (c + 1)] = xs[j];
    }
    const float SC[4] = {-L2E, -L2E, -L2E, SGK};
    float wg[4][9], bb[4];
#pragma unroll
    for (int g = 0; g < 4; ++g) {
        bb[g] = b0[g] * SC[g];
#pragma unroll
        for (int k = 0; k < 9; ++k) wg[g][k] = w0[(g * 2 + 0) * 9 + k] * SC[g];
    }
    __syncthreads();
    f4* __restrict__ zt = (f4*)zx + (size_t)t * NCELL;
    for (int cell = tid; cell < NCELL; cell += 256) {
        const int r = cell / NCOL, c = cell % NCOL;
        const int p = (r + 1) * PPW + (c + 1);
        float z0 = bb[0], z1 = bb[1], z2 = bb[2], z3 = bb[3];
#pragma unroll
        for (int ky = 0; ky < 3; ++ky)
#pragma unroll
            for (int kx = 0; kx < 3; ++kx) {
                const float v = xf[p + (ky - 1) * PPW + (kx - 1)];
                const int k = ky * 3 + kx;
                z0 += wg[0][k] * v; z1 += wg[1][k] * v;
                z2 += wg[2][k] * v; z3 += wg[3][k] * v;
            }
        zt[cell] = (f4){z0, z1, z2, z3};
    }
}

// ============================================================================
// 2-CU pipelined scan, REBALANCED: producer does layer0 + layer1's x-conv and
// publishes U[t] = b1 + Wx1*conv(h0[t]) into the consumed zx[t] slot (32 KB,
// same cell*16 layout as zx). Consumer = U prefetch + h-conv + gates only.
// One barrier/step on each side.
// ============================================================================
__global__ __launch_bounds__(NTHR, 2) void convlstm_pipe7(
        float* zxrw,
        const float* __restrict__ w0g,
        const float* __restrict__ w1g, const float* __restrict__ b1g,
        float* __restrict__ feat, int* flags) {
    __shared__ float P0[2][10][2][64];     // producer h0 halos
    __shared__ float P1[2][10][2][64];     // consumer h1 halos

    const int tid = threadIdx.x;
    const int w = tid >> 6;
    const int c = tid & 63;
    const bool colok = (c < NCOL);
    const float maskf = colok ? 1.f : 0.f;
    const int cmin = colok ? c : (NCOL - 1);

    {   // zero LDS (pad rows stay zero forever)
        float* p0 = &P0[0][0][0][0];
        float* p1 = &P1[0][0][0][0];
        for (int i = tid; i < 2 * 10 * 2 * 64; i += NTHR) { p0[i] = 0.f; p1[i] = 0.f; }
    }

    float sgkv = SGK;
    asm volatile("" : "+v"(sgkv));
    const float SA = -L2E;

    if (blockIdx.x == 0) {
        // ============ producer : layer 0 + layer-1 x-conv ============
        f2 Wh0a[9], Wh0b[9];
#pragma unroll
        for (int k = 0; k < 9; ++k) {
            Wh0a[k] = (f2){w0g[ 9 + k] * SA, w0g[27 + k] * SA};
            Wh0b[k] = (f2){w0g[45 + k] * SA, w0g[63 + k] * SGK};
        }
#pragma unroll
        for (int k = 0; k < 9; ++k)
            asm volatile("" : "+v"(Wh0a[k]), "+v"(Wh0b[k]));

        i64 Sx1a[9], Sx1b[9];
#pragma unroll
        for (int k = 0; k < 9; ++k) {
            Sx1a[k] = mk_sw(w1g[ 0 + k] * SA, w1g[18 + k] * SA);
            Sx1b[k] = mk_sw(w1g[36 + k] * SA, w1g[54 + k] * SGK);
        }
        f2 B1a = (f2){b1g[0] * SA, b1g[1] * SA};
        f2 B1b = (f2){b1g[2] * SA, b1g[3] * SGK};
        asm volatile("" : "+v"(B1a), "+v"(B1b));

        float h0[5] = {0,0,0,0,0}, c0[5] = {0,0,0,0,0};

        const char* zb = (const char*)zxrw;
        int voff = ((w * 5) * NCOL + cmin) * 16;
        f2 zA[5], zB[5];
        {
            const char* p = zb + voff;
#pragma unroll
            for (int i = 0; i < 5; ++i) {
                const f4 z4 = *(const f4*)(p + i * 800);
                zA[i] = __builtin_shufflevector(z4, z4, 0, 1);
                zB[i] = __builtin_shufflevector(z4, z4, 2, 3);
            }
        }
        voff += 32000;

        __syncthreads();

        for (int t = 0; t < TSTEPS; ++t) {
            const int pn = t & 1, pr_ = pn ^ 1;

            // ---- layer 0: h-conv + gates ----
            {
                float e0[7];
                e0[0] = P0[pr_][w][1][c];
                e0[6] = P0[pr_][w + 2][0][c];
#pragma unroll
                for (int i = 0; i < 5; ++i) e0[i + 1] = h0[i];
                conv5_v(e0, Wh0a, Wh0b, zA, zB);
            }
#pragma unroll
            for (int i = 0; i < 5; ++i)
                h0[i] = gates_update(zA[i], zB[i], c0[i], maskf, sgkv);
            P0[pn][w + 1][0][c] = h0[0];
            P0[pn][w + 1][1][c] = h0[4];

            ldsbar();              // the one barrier: new h0 halos visible

            // ---- layer-1 x-conv on h0[t] (fresh halos) -> publish U[t] ----
            {
                float ex[7];
                ex[0] = P0[pn][w][1][c];
                ex[6] = P0[pn][w + 2][0][c];
#pragma unroll
                for (int i = 0; i < 5; ++i) ex[i + 1] = h0[i];
                f2 uA[5], uB[5];
                conv5_s<true>(ex, Sx1a, Sx1b, uA, uB, B1a, B1b);
                if (colok) {
                    f4* up = (f4*)((char*)zxrw + (size_t)t * 32000) + (w * 5) * NCOL + c;
#pragma unroll
                    for (int i = 0; i < 5; ++i)
                        up[i * NCOL] = (f4){uA[i].x, uA[i].y, uB[i].x, uB[i].y};
                }
            }

            // prefetch zx[t+1] (rides across barriers; own cells only)
            {
                const char* p = zb + voff;
#pragma unroll
                for (int i = 0; i < 5; ++i) {
                    const f4 z4 = *(const f4*)(p + i * 800);
                    zA[i] = __builtin_shufflevector(z4, z4, 0, 1);
                    zB[i] = __builtin_shufflevector(z4, z4, 2, 3);
                }
                if (t + 2 < TSTEPS) voff += 32000;
            }

            if ((t & (CHUNK - 1)) == (CHUNK - 1)) {
                // chunk boundary: drain U stores, then one RELEASE flag
                asm volatile("s_waitcnt vmcnt(0) lgkmcnt(0)\n\ts_barrier" ::: "memory");
                if (tid == 0)
                    __hip_atomic_store(&flags[0], t + 1,
                                       __ATOMIC_RELEASE, __HIP_MEMORY_SCOPE_AGENT);
            }
            // non-boundary steps: no end barrier needed (parity double-buffer;
            // the mid-step barrier provides the cross-step ordering)
        }
    } else {
        // ============ consumer : layer 1 h-conv + gates ============
        i64 Sh1a[9], Sh1b[9];
#pragma unroll
        for (int k = 0; k < 9; ++k) {
            Sh1a[k] = mk_sw(w1g[ 9 + k] * SA, w1g[27 + k] * SA);
            Sh1b[k] = mk_sw(w1g[45 + k] * SA, w1g[63 + k] * SGK);
        }
        const f2 Zf2 = (f2){0.f, 0.f};

        float h1[5] = {0,0,0,0,0}, c1[5] = {0,0,0,0,0};

        const char* zb = (const char*)zxrw;
        int voff = ((w * 5) * NCOL + cmin) * 16;

        __syncthreads();   // LDS zero visible

        // initial acquire: watermark covers 2 chunks -> prefetch t+1 always legal
        {
            const int tgt0 = (2 * CHUNK < TSTEPS) ? 2 * CHUNK : TSTEPS;
            while (__hip_atomic_load(&flags[0], __ATOMIC_ACQUIRE,
                                     __HIP_MEMORY_SCOPE_AGENT) < tgt0)
                __builtin_amdgcn_s_sleep(8);
        }
        // load U[0]
        f2 zA[5], zB[5];
        {
            const char* p = zb + voff;
#pragma unroll
            for (int i = 0; i < 5; ++i) {
                const f4 z4 = *(const f4*)(p + i * 800);
                zA[i] = __builtin_shufflevector(z4, z4, 0, 1);
                zB[i] = __builtin_shufflevector(z4, z4, 2, 3);
            }
        }
        voff += 32000;

        for (int tc = 0; tc < TSTEPS; tc += CHUNK) {
            if (tc > 0) {
                int tgt = tc + 2 * CHUNK;
                if (tgt > TSTEPS) tgt = TSTEPS;
                while (__hip_atomic_load(&flags[0], __ATOMIC_ACQUIRE,
                                         __HIP_MEMORY_SCOPE_AGENT) < tgt)
                    __builtin_amdgcn_s_sleep(8);
            }

            for (int t = tc; t < tc + CHUNK; ++t) {
                const int pn = t & 1, pr_ = pn ^ 1;

                // h-conv accumulates into the loaded U (bias + x-conv already in)
                {
                    float eh[7];
                    eh[0] = P1[pr_][w][1][c];
                    eh[6] = P1[pr_][w + 2][0][c];
#pragma unroll
                    for (int i = 0; i < 5; ++i) eh[i + 1] = h1[i];
                    conv5_s<false>(eh, Sh1a, Sh1b, zA, zB, Zf2, Zf2);
                }
#pragma unroll
                for (int i = 0; i < 5; ++i)
                    h1[i] = gates_update(zA[i], zB[i], c1[i], maskf, sgkv);
                P1[pn][w + 1][0][c] = h1[0];
                P1[pn][w + 1][1][c] = h1[4];

                // prefetch U[t+1] into the consumed zA/zB (rides across barrier)
                {
                    const int tn = (t + 1 < TSTEPS) ? (t + 1) : (TSTEPS - 1);
                    const char* p = (const char*)zxrw + (size_t)tn * 32000 +
                                    ((w * 5) * NCOL + cmin) * 16;
#pragma unroll
                    for (int i = 0; i < 5; ++i) {
                        const f4 z4 = *(const f4*)(p + i * 800);
                        zA[i] = __builtin_shufflevector(z4, z4, 0, 1);
                        zB[i] = __builtin_shufflevector(z4, z4, 2, 3);
                    }
                }

                ldsbar();          // P1 parity barrier; prefetch stays in flight
            }
        }

        if (colok) {
#pragma unroll
            for (int i = 0; i < 5; ++i)
                feat[(w * 5 + i) * NCOL + c] = h1[i];
        }
    }
}

// ============================================================================
// Single-CU scan fallback (round-11 structure)
// ============================================================================
__global__ __launch_bounds__(NTHR, 2) void convlstm_scan5(
        const float* __restrict__ zx,
        const float* __restrict__ w0g,
        const float* __restrict__ w1g, const float* __restrict__ b1g,
        float* __restrict__ feat) {
    __shared__ float P0[2][10][2][64];
    __shared__ float P1[2][10][2][64];

    const int tid = threadIdx.x;
    const int w = tid >> 6;
    const int c = tid & 63;
    const float maskf = (c < NCOL) ? 1.f : 0.f;
    const int cmin = (c < NCOL) ? c : (NCOL - 1);

    {
        float* p0 = &P0[0][0][0][0];
        float* p1 = &P1[0][0][0][0];
        for (int i = tid; i < 2 * 10 * 2 * 64; i += NTHR) { p0[i] = 0.f; p1[i] = 0.f; }
    }

    const float SA = -L2E;
    f2 Wh0a[9], Wh0b[9];
#pragma unroll
    for (int k = 0; k < 9; ++k) {
        Wh0a[k] = (f2){w0g[ 9 + k] * SA, w0g[27 + k] * SA};
        Wh0b[k] = (f2){w0g[45 + k] * SA, w0g[63 + k] * SGK};
    }
#pragma unroll
    for (int k = 0; k < 9; ++k)
        asm volatile("" : "+v"(Wh0a[k]), "+v"(Wh0b[k]));

    i64 Sx1a[9], Sx1b[9], Sh1a[9], Sh1b[9];
#pragma unroll
    for (int k = 0; k < 9; ++k) {
        Sx1a[k] = mk_sw(w1g[ 0 + k] * SA, w1g[18 + k] * SA);
        Sx1b[k] = mk_sw(w1g[36 + k] * SA, w1g[54 + k] * SGK);
        Sh1a[k] = mk_sw(w1g[ 9 + k] * SA, w1g[27 + k] * SA);
        Sh1b[k] = mk_sw(w1g[45 + k] * SA, w1g[63 + k] * SGK);
    }
    f2 B1a = (f2){b1g[0] * SA, b1g[1] * SA};
    f2 B1b = (f2){b1g[2] * SA, b1g[3] * SGK};
    asm volatile("" : "+v"(B1a), "+v"(B1b));

    float sgkv = SGK;
    asm volatile("" : "+v"(sgkv));

    float h0[5] = {0,0,0,0,0}, c0[5] = {0,0,0,0,0};
    float h1[5] = {0,0,0,0,0}, c1[5] = {0,0,0,0,0};

    const char* __restrict__ zb = (const char*)zx;
    int voff = ((w * 5) * NCOL + cmin) * 16;

    f2 zA[5], zB[5];
    {
        const char* p = zb + voff;
#pragma unroll
        for (int i = 0; i < 5; ++i) {
            const f4 z4 = *(const f4*)(p + i * 800);
            zA[i] = __builtin_shufflevector(z4, z4, 0, 1);
            zB[i] = __builtin_shufflevector(z4, z4, 2, 3);
        }
    }
    voff += 32000;

    __syncthreads();

    for (int t = 0; t < TSTEPS; ++t) {
        const int pn = t & 1, pr_ = pn ^ 1;
        {
            float e0[7];
            e0[0] = P0[pr_][w][1][c];
            e0[6] = P0[pr_][w + 2][0][c];
#pragma unroll
            for (int i = 0; i < 5; ++i) e0[i + 1] = h0[i];
            conv5_v(e0, Wh0a, Wh0b, zA, zB);
        }
#pragma unroll
        for (int i = 0; i < 5; ++i)
            h0[i] = gates_update(zA[i], zB[i], c0[i], maskf, sgkv);
        P0[pn][w + 1][0][c] = h0[0];
        P0[pn][w + 1][1][c] = h0[4];
        {
            const char* p = zb + voff;
#pragma unroll
            for (int i = 0; i < 5; ++i) {
                const f4 z4 = *(const f4*)(p + i * 800);
                zA[i] = __builtin_shufflevector(z4, z4, 0, 1);
                zB[i] = __builtin_shufflevector(z4, z4, 2, 3);
            }
            if (t + 2 < TSTEPS) voff += 32000;
        }
        ldsbar();
        f2 uA[5], uB[5];
        {
            float ex[7];
            ex[0] = P0[pn][w][1][c];
            ex[6] = P0[pn][w + 2][0][c];
#pragma unroll
            for (int i = 0; i < 5; ++i) ex[i + 1] = h0[i];
            conv5_s<true>(ex, Sx1a, Sx1b, uA, uB, B1a, B1b);
        }
        {
            float eh[7];
            eh[0] = P1[pr_][w][1][c];
            eh[6] = P1[pr_][w + 2][0][c];
#pragma unroll
            for (int i = 0; i < 5; ++i) eh[i + 1] = h1[i];
            conv5_s<false>(eh, Sh1a, Sh1b, uA, uB, B1a, B1b);
        }
#pragma unroll
        for (int i = 0; i < 5; ++i)
            h1[i] = gates_update(uA[i], uB[i], c1[i], maskf, sgkv);
        P1[pn][w + 1][0][c] = h1[0];
        P1[pn][w + 1][1][c] = h1[4];
        ldsbar();
    }

    if (c < NCOL) {
#pragma unroll
        for (int i = 0; i < 5; ++i)
            feat[(w * 5 + i) * NCOL + c] = h1[i];
    }
}

// ============================================================================
// Fallback monolithic scan (round-1, known-correct; used only if ws too small)
// ============================================================================
#define PW 52
#define PH 42
__device__ __forceinline__ void cell_update(const float* __restrict__ xf,
                                            const float* __restrict__ hf,
                                            const float (&wr)[72], const float (&br)[4],
                                            const int (&pidx)[4],
                                            float (&cst)[4], float (&hn)[4]) {
#pragma unroll
    for (int q = 0; q < 4; ++q) {
        const int p = pidx[q];
        float z0 = br[0], z1 = br[1], z2 = br[2], z3 = br[3];
#pragma unroll
        for (int ky = 0; ky < 3; ++ky)
#pragma unroll
            for (int kx = 0; kx < 3; ++kx) {
                const int off = (ky - 1) * PW + (kx - 1);
                const float xval = xf[p + off];
                const float hval = hf[p + off];
                const int wi = ky * 3 + kx;
                z0 += wr[ 0 + wi] * xval + wr[ 9 + wi] * hval;
                z1 += wr[18 + wi] * xval + wr[27 + wi] * hval;
                z2 += wr[36 + wi] * xval + wr[45 + wi] * hval;
                z3 += wr[54 + wi] * xval + wr[63 + wi] * hval;
            }
        const float ig = sigm(z0), fg = sigm(z1), og = sigm(z2), gg = tanh_f(z3);
        const float cn = fg * cst[q] + ig * gg;
        cst[q] = cn;
        hn[q]  = og * tanh_f(cn);
    }
}

__global__ __launch_bounds__(NTHR, 2) void convlstm_scan(
    const float* __restrict__ s,
    const float* __restrict__ w0g, const float* __restrict__ b0g,
    const float* __restrict__ w1g, const float* __restrict__ b1g,
    float* __restrict__ feat) {
    __shared__ float xb[PH * PW];
    __shared__ float h0[PH * PW];
    __shared__ float h1[PH * PW];
    const int tid = threadIdx.x;
    for (int i = tid; i < PH * PW; i += NTHR) { xb[i] = 0.f; h0[i] = 0.f; h1[i] = 0.f; }
    float w0r[72], w1r[72], b0r[4], b1r[4];
#pragma unroll
    for (int i = 0; i < 72; ++i) w0r[i] = w0g[i];
#pragma unroll
    for (int i = 0; i < 72; ++i) w1r[i] = w1g[i];
#pragma unroll
    for (int i = 0; i < 4; ++i) { b0r[i] = b0g[i]; b1r[i] = b1g[i]; }
    int pidx[4]; bool cv[4];
#pragma unroll
    for (int q = 0; q < 4; ++q) {
        int cell = tid + q * NTHR;
        cv[q] = (cell < NCELL);
        if (!cv[q]) cell = 0;
        const int r = cell / NCOL, cc = cell % NCOL;
        pidx[q] = (r + 1) * PW + (cc + 1);
    }
    int xjj[4], xpp[4]; bool xv[4];
#pragma unroll
    for (int k = 0; k < 4; ++k) {
        int j = tid + k * NTHR;
        xv[k] = (j < INLEN);
        if (!xv[k]) j = 0;
        xjj[k] = j;
        const int r = j / NCOL, cc = j % NCOL;
        xpp[k] = (r + 1) * PW + (cc + 1);
    }
    float c0r[4] = {0,0,0,0}, c1r[4] = {0,0,0,0};
    float xr[4];
#pragma unroll
    for (int k = 0; k < 4; ++k) xr[k] = xv[k] ? s[xjj[k]] : 0.f;
    __syncthreads();
    for (int t = 0; t < TSTEPS; ++t) {
#pragma unroll
        for (int k = 0; k < 4; ++k)
            if (xv[k]) xb[xpp[k]] = xr[k];
        {
            const size_t bofs = (size_t)(t + 1 < TSTEPS ? t + 1 : t) * INLEN;
#pragma unroll
            for (int k = 0; k < 4; ++k) xr[k] = xv[k] ? s[bofs + xjj[k]] : 0.f;
        }
        __syncthreads();
        float hn0[4];
        cell_update(xb, h0, w0r, b0r, pidx, c0r, hn0);
        __syncthreads();
#pragma unroll
        for (int q = 0; q < 4; ++q)
            if (cv[q]) h0[pidx[q]] = hn0[q];
        __syncthreads();
        float hn1[4];
        cell_update(h0, h1, w1r, b1r, pidx, c1r, hn1);
        __syncthreads();
#pragma unroll
        for (int q = 0; q < 4; ++q)
            if (cv[q]) h1[pidx[q]] = hn1[q];
    }
#pragma unroll
    for (int q = 0; q < 4; ++q)
        if (cv[q]) feat[tid + q * NTHR] = h1[pidx[q]];
}

// ============================================================================
// FC epilogue
// ============================================================================
__global__ __launch_bounds__(256) void fc_kernel(const float* __restrict__ feat,
                                                 const float* __restrict__ w,
                                                 const float* __restrict__ b,
                                                 float* __restrict__ out) {
    const int j   = blockIdx.x;
    const int tid = threadIdx.x;
    const float* __restrict__ wr = w + (size_t)j * NCELL;
    float acc = 0.f;
    for (int k = tid; k < NCELL; k += 256) {
        float f = feat[k];
        f = (f > 0.f) ? f : 0.01f * f;
        acc += f * wr[k];
    }
#pragma unroll
    for (int off = 32; off > 0; off >>= 1) acc += __shfl_down(acc, off, 64);
    __shared__ float red[4];
    const int wv = tid >> 6, ln = tid & 63;
    if (ln == 0) red[wv] = acc;
    __syncthreads();
    if (tid == 0) {
        const float a = red[0] + red[1] + red[2] + red[3] + b[j];
        out[j] = fastrcp(1.0f + __expf(-a));
    }
}

extern "C" void kernel_launch(void* const* d_in, const int* in_sizes, int n_in,
                              void* d_out, int out_size, void* d_ws, size_t ws_size,
                              hipStream_t stream) {
    const float* s   = (const float*)d_in[0];
    const float* w0  = (const float*)d_in[1];
    const float* b0  = (const float*)d_in[2];
    const float* w1  = (const float*)d_in[3];
    const float* b1  = (const float*)d_in[4];
    const float* fcw = (const float*)d_in[5];
    const float* fcb = (const float*)d_in[6];
    float* out  = (float*)d_out;
    float* feat = (float*)d_ws;   // 2000 floats

    const size_t zx_bytes = (size_t)TSTEPS * NCELL * 4 * sizeof(float);
    if (ws_size >= zx_bytes + ZX_OFF) {
        // 2-CU rebalanced pipeline
        int*   flags = (int*)((char*)d_ws + FLAGS_OFF);
        float* zx    = (float*)((char*)d_ws + ZX_OFF);
        zx_prepass4<<<TSTEPS, 256, 0, stream>>>(s, w0, b0, zx, flags);
        convlstm_pipe7<<<2, NTHR, 0, stream>>>(zx, w0, w1, b1, feat, flags);
    } else if (ws_size >= zx_bytes + 8192) {
        int*   flags = (int*)((char*)d_ws + 4096);
        float* zx    = (float*)((char*)d_ws + 8192);
        zx_prepass4<<<TSTEPS, 256, 0, stream>>>(s, w0, b0, zx, flags);
        convlstm_scan5<<<1, NTHR, 0, stream>>>(zx, w0, w1, b1, feat);
    } else {
        convlstm_scan<<<1, NTHR, 0, stream>>>(s, w0, b0, w1, b1, feat);
    }
    fc_kernel<<<NCELL, 256, 0, stream>>>(feat, fcw, fcb, out);
}

// Round 15
// 5503.313 us; speedup vs baseline: 1.3072x; 1.3072x over previous
//
#include <hip/hip_runtime.h>
#include <cstddef>

#define TSTEPS 4096
#define INLEN  1910
#define NROW   40
#define NCOL   50
#define NCELL  2000
#define NTHR   512
#define CHUNK  16          // producer->consumer flag amortization

// padded field dims for the pre-pass
#define PPH 42
#define PPW 52

typedef float f2 __attribute__((ext_vector_type(2)));
typedef float f4 __attribute__((ext_vector_type(4)));
typedef long long i64;

#define L2E  1.4426950408889634f
#define SGK  (-2.f * L2E)          // scale applied to tanh() args (and c-state)

// d_ws layout (pipe path): [0,8000) feat | [8192,8704) flags | [16384, +zx) zx/h0-ring
#define FLAGS_OFF 8192
#define ZX_OFF    16384

// ---------- math helpers ----------
__device__ __forceinline__ float fastrcp(float x)  { return __builtin_amdgcn_rcpf(x); }
__device__ __forceinline__ float fastexp2(float x) { return __builtin_amdgcn_exp2f(x); }
// legacy (fallback kernel + fc)
__device__ __forceinline__ float sigm(float x)   { return fastrcp(1.0f + __expf(-x)); }
__device__ __forceinline__ float tanh_f(float x) { return 2.0f * fastrcp(1.0f + __expf(-2.0f * x)) - 1.0f; }

// LDS-only barrier: orders LDS ops but lets global loads/stores stay in flight
// (__syncthreads drains vmcnt(0) too -> ~500-900 cyc stall on in-flight prefetch)
__device__ __forceinline__ void ldsbar() {
    asm volatile("s_waitcnt lgkmcnt(0)\n\ts_barrier" ::: "memory");
}

// ---------- DPP full-wave lane shifts (zero fill at wave ends) ----------
__device__ __forceinline__ float lane_left(float x) {   // lane i <- lane i-1; lane0 -> 0
    int r = __builtin_amdgcn_update_dpp(0, __builtin_bit_cast(int, x),
                                        0x138 /*WAVE_SHR1*/, 0xF, 0xF, true);
    return __builtin_bit_cast(float, r);
}
__device__ __forceinline__ float lane_right(float x) {  // lane i <- lane i+1; lane63 -> 0
    int r = __builtin_amdgcn_update_dpp(0, __builtin_bit_cast(int, x),
                                        0x130 /*WAVE_SHL1*/, 0xF, 0xF, true);
    return __builtin_bit_cast(float, r);
}

// packed fp32 FMA; VOP3P requires 64-bit-pair operands, so the value goes in
// an f2 whose LO half carries the data (op_sel_hi[src1]=0 broadcasts lo).
__device__ __forceinline__ void pkfma_v(f2 &acc, f2 w, f2 vlo) {
    asm("v_pk_fma_f32 %0, %1, %2, %0 op_sel_hi:[1,0,1]" : "+v"(acc) : "v"(w), "v"(vlo));
}
__device__ __forceinline__ void pkfma_s(f2 &acc, i64 w, f2 vlo) {
    asm("v_pk_fma_f32 %0, %1, %2, %0 op_sel_hi:[1,0,1]" : "+v"(acc) : "s"(w), "v"(vlo));
}
__device__ __forceinline__ f2 pkfma3_s(i64 w, f2 vlo, f2 B) {
    f2 d;
    asm("v_pk_fma_f32 %0, %1, %2, %3 op_sel_hi:[1,0,1]" : "=v"(d) : "s"(w), "v"(vlo), "v"(B));
    return d;
}

// pack two uniform floats into an SGPR pair
__device__ __forceinline__ i64 mk_sw(float lo, float hi) {
    int l = __builtin_amdgcn_readfirstlane(__builtin_bit_cast(int, lo));
    int h = __builtin_amdgcn_readfirstlane(__builtin_bit_cast(int, hi));
    return (i64)((unsigned long long)(unsigned)l | ((unsigned long long)(unsigned)h << 32));
}

// 3x3 conv over 7 stencil rows -> 5 output rows; VGPR weights
__device__ __forceinline__ void conv5_v(const float (&e)[7], const f2 (&Wa)[9], const f2 (&Wb)[9],
                                        f2 (&aA)[5], f2 (&aB)[5]) {
#pragma unroll
    for (int rr = 0; rr < 7; ++rr) {
        f2 Lv, Ev, Rv;                 // hi halves unused (op_sel broadcast reads lo)
        Lv.x = lane_left(e[rr]);
        Ev.x = e[rr];
        Rv.x = lane_right(e[rr]);
        const int ilo = (rr - 2 > 0) ? (rr - 2) : 0;
        const int ihi = (rr < 4) ? rr : 4;
#pragma unroll
        for (int i = ilo; i <= ihi; ++i) {
            const int k = (rr - i) * 3;
            pkfma_v(aA[i], Wa[k],     Lv);
            pkfma_v(aA[i], Wa[k + 1], Ev);
            pkfma_v(aA[i], Wa[k + 2], Rv);
            pkfma_v(aB[i], Wb[k],     Lv);
            pkfma_v(aB[i], Wb[k + 1], Ev);
            pkfma_v(aB[i], Wb[k + 2], Rv);
        }
    }
}

// SGPR-weight conv; INIT=true initializes acc i at its first tap with bias B
template<bool INIT>
__device__ __forceinline__ void conv5_s(const float (&e)[7], const i64 (&Wa)[9], const i64 (&Wb)[9],
                                        f2 (&aA)[5], f2 (&aB)[5], f2 Ba, f2 Bb) {
#pragma unroll
    for (int rr = 0; rr < 7; ++rr) {
        f2 Lv, Ev, Rv;
        Lv.x = lane_left(e[rr]);
        Ev.x = e[rr];
        Rv.x = lane_right(e[rr]);
        const int ilo = (rr - 2 > 0) ? (rr - 2) : 0;
        const int ihi = (rr < 4) ? rr : 4;
#pragma unroll
        for (int i = ilo; i <= ihi; ++i) {
            const int k = (rr - i) * 3;
            if (INIT && rr == i) {     // first touch of acc i
                aA[i] = pkfma3_s(Wa[k], Lv, Ba);
                aB[i] = pkfma3_s(Wb[k], Lv, Bb);
            } else {
                pkfma_s(aA[i], Wa[k], Lv);
                pkfma_s(aB[i], Wb[k], Lv);
            }
            pkfma_s(aA[i], Wa[k + 1], Ev);
            pkfma_s(aA[i], Wa[k + 2], Rv);
            pkfma_s(aB[i], Wb[k + 1], Ev);
            pkfma_s(aB[i], Wb[k + 2], Rv);
        }
    }
}

// Fused LSTM gate update, 7 transcendentals (5 exp2 + 2 rcp).
// zA={i',f'}, zB={o',g'} pre-scaled by -L2E (i,f,o) / SGK (g).
// c-state cs stored PRE-SCALED by SGK. Returns h (masked).
__device__ __forceinline__ float gates_update(f2 zA, f2 zB, float &cs, float maskf, float sgkv) {
    const float ea = fastexp2(zA.x);           // e^-i
    const float eb = fastexp2(zA.y);           // e^-f
    const float ec = fastexp2(zB.x);           // e^-o
    const float ed = fastexp2(zB.y);           // e^-2g
    const float Q  = 1.f + eb;
    const float P1 = (1.f + ea) * (1.f + ed);
    const float r1 = fastrcp(Q * P1);
    const float sf = P1 * r1;                  // sigmoid(f)
    const float nm = ed * (2.f * L2E) + sgkv;  // SGK*(1-ed)
    const float sitgS = Q * nm * r1;           // SGK * sigmoid(i)*tanh(g)
    cs = sf * cs + sitgS;                      // SGK * c_new
    const float ee = fastexp2(cs);             // e^-2c
    const float r2 = fastrcp((1.f + ec) * (1.f + ee));
    return (1.f - ee) * r2 * maskf;            // sigmoid(o)*tanh(c)
}

// ============================================================================
// Pre-pass: zx[t][cell] = f4{i,f,o,g} pre-activations of layer-0 x-conv,
// PRE-SCALED by {-L2E,-L2E,-L2E,SGK}. Also zeroes the pipe flags (block 0).
// ============================================================================
__global__ __launch_bounds__(256) void zx_prepass4(const float* __restrict__ s,
                                                   const float* __restrict__ w0,
                                                   const float* __restrict__ b0,
                                                   float* __restrict__ zx,
                                                   int* __restrict__ flags) {
    __shared__ float xf[PPH * PPW];
    const int t = blockIdx.x;
    const int tid = threadIdx.x;
    if (t == 0 && tid < 8) flags[tid * 16] = 0;   // reset pipe flags each launch
    for (int i = tid; i < PPH * PPW; i += 256) xf[i] = 0.f;
    __syncthreads();
    const float* __restrict__ xs = s + (size_t)t * INLEN;
    for (int j = tid; j < INLEN; j += 256) {
        const int r = j / NCOL, c = j % NCOL;
        xf[(r + 1) * PPW + (c + 1)] = xs[j];
    }
    const float SC[4] = {-L2E, -L2E, -L2E, SGK};
    float wg[4][9], bb[4];
#pragma unroll
    for (int g = 0; g < 4; ++g) {
        bb[g] = b0[g] * SC[g];
#pragma unroll
        for (int k = 0; k < 9; ++k) wg[g][k] = w0[(g * 2 + 0) * 9 + k] * SC[g];
    }
    __syncthreads();
    f4* __restrict__ zt = (f4*)zx + (size_t)t * NCELL;
    for (int cell = tid; cell < NCELL; cell += 256) {
        const int r = cell / NCOL, c = cell % NCOL;
        const int p = (r + 1) * PPW + (c + 1);
        float z0 = bb[0], z1 = bb[1], z2 = bb[2], z3 = bb[3];
#pragma unroll
        for (int ky = 0; ky < 3; ++ky)
#pragma unroll
            for (int kx = 0; kx < 3; ++kx) {
                const float v = xf[p + (ky - 1) * PPW + (kx - 1)];
                const int k = ky * 3 + kx;
                z0 += wg[0][k] * v; z1 += wg[1][k] * v;
                z2 += wg[2][k] * v; z3 += wg[3][k] * v;
            }
        zt[cell] = (f4){z0, z1, z2, z3};
    }
}

// ============================================================================
// 2-CU pipelined scan, CHUNKED handshake + consumer h0 prefetch + LDS-only
// per-step barriers (global prefetch rides across s_barrier).
// ============================================================================
__global__ __launch_bounds__(NTHR, 2) void convlstm_pipe4(
        float* zxrw,                       // zx + h0 ring (aliased regions; no restrict)
        const float* __restrict__ w0g,
        const float* __restrict__ w1g, const float* __restrict__ b1g,
        float* __restrict__ feat, int* flags) {
    __shared__ float P0[2][10][2][64];     // producer h0 halos
    __shared__ float P1[2][10][2][64];     // consumer h1 halos

    const int tid = threadIdx.x;
    const int w = tid >> 6;
    const int c = tid & 63;
    const bool colok = (c < NCOL);
    const float maskf = colok ? 1.f : 0.f;
    const int cmin = colok ? c : (NCOL - 1);

    {   // zero LDS (pad rows stay zero forever)
        float* p0 = &P0[0][0][0][0];
        float* p1 = &P1[0][0][0][0];
        for (int i = tid; i < 2 * 10 * 2 * 64; i += NTHR) { p0[i] = 0.f; p1[i] = 0.f; }
    }

    float sgkv = SGK;
    asm volatile("" : "+v"(sgkv));
    const float SA = -L2E;

    if (blockIdx.x == 0) {
        // ======================= producer : layer 0 =======================
        f2 Wh0a[9], Wh0b[9];
#pragma unroll
        for (int k = 0; k < 9; ++k) {
            Wh0a[k] = (f2){w0g[ 9 + k] * SA, w0g[27 + k] * SA};
            Wh0b[k] = (f2){w0g[45 + k] * SA, w0g[63 + k] * SGK};
        }
#pragma unroll
        for (int k = 0; k < 9; ++k)
            asm volatile("" : "+v"(Wh0a[k]), "+v"(Wh0b[k]));

        float h0[5] = {0,0,0,0,0}, c0[5] = {0,0,0,0,0};

        const char* zb = (const char*)zxrw;
        int voff = ((w * 5) * NCOL + cmin) * 16;
        f2 zA[5], zB[5];
        {
            const char* p = zb + voff;
#pragma unroll
            for (int i = 0; i < 5; ++i) {
                const f4 z4 = *(const f4*)(p + i * 800);
                zA[i] = __builtin_shufflevector(z4, z4, 0, 1);
                zB[i] = __builtin_shufflevector(z4, z4, 2, 3);
            }
        }
        voff += 32000;

        __syncthreads();

        for (int t = 0; t < TSTEPS; ++t) {
            const int pn = t & 1, pr_ = pn ^ 1;
            {
                float e0[7];
                e0[0] = P0[pr_][w][1][c];
                e0[6] = P0[pr_][w + 2][0][c];
#pragma unroll
                for (int i = 0; i < 5; ++i) e0[i + 1] = h0[i];
                conv5_v(e0, Wh0a, Wh0b, zA, zB);
            }
#pragma unroll
            for (int i = 0; i < 5; ++i)
                h0[i] = gates_update(zA[i], zB[i], c0[i], maskf, sgkv);
            P0[pn][w + 1][0][c] = h0[0];
            P0[pn][w + 1][1][c] = h0[4];

            // publish h0[t] into the consumed zx[t] slot (plain cacheable stores)
            if (colok) {
                float* hp = (float*)((char*)zxrw + (size_t)t * 32000) + (w * 5) * NCOL + c;
                hp[0 * NCOL] = h0[0];
                hp[1 * NCOL] = h0[1];
                hp[2 * NCOL] = h0[2];
                hp[3 * NCOL] = h0[3];
                hp[4 * NCOL] = h0[4];
            }

            // prefetch zx[t+1] (stays in flight across the LDS-only barrier)
            {
                const char* p = zb + voff;
#pragma unroll
                for (int i = 0; i < 5; ++i) {
                    const f4 z4 = *(const f4*)(p + i * 800);
                    zA[i] = __builtin_shufflevector(z4, z4, 0, 1);
                    zB[i] = __builtin_shufflevector(z4, z4, 2, 3);
                }
                if (t + 2 < TSTEPS) voff += 32000;
            }

            if ((t & (CHUNK - 1)) == (CHUNK - 1)) {
                // chunk boundary: full drain, then one RELEASE flag
                asm volatile("s_waitcnt vmcnt(0) lgkmcnt(0)\n\ts_barrier" ::: "memory");
                if (tid == 0)
                    __hip_atomic_store(&flags[0], t + 1,
                                       __ATOMIC_RELEASE, __HIP_MEMORY_SCOPE_AGENT);
            } else {
                ldsbar();                  // P0 parity barrier, LDS-only drain
            }
        }
    } else {
        // ======================= consumer : layer 1 =======================
        i64 Sx1a[9], Sx1b[9], Sh1a[9], Sh1b[9];
#pragma unroll
        for (int k = 0; k < 9; ++k) {
            Sx1a[k] = mk_sw(w1g[ 0 + k] * SA, w1g[18 + k] * SA);
            Sx1b[k] = mk_sw(w1g[36 + k] * SA, w1g[54 + k] * SGK);
            Sh1a[k] = mk_sw(w1g[ 9 + k] * SA, w1g[27 + k] * SA);
            Sh1b[k] = mk_sw(w1g[45 + k] * SA, w1g[63 + k] * SGK);
        }
        f2 B1a = (f2){b1g[0] * SA, b1g[1] * SA};
        f2 B1b = (f2){b1g[2] * SA, b1g[3] * SGK};
        asm volatile("" : "+v"(B1a), "+v"(B1b));

        float h1[5] = {0,0,0,0,0}, c1[5] = {0,0,0,0,0};

        // hoisted h0-row offsets + validity masks (loop-invariant)
        int   roff[7];
        float rmask[7];
#pragma unroll
        for (int j = 0; j < 7; ++j) {
            const int rg = 5 * w - 1 + j;
            const bool v = (rg >= 0) && (rg < NROW) && colok;
            roff[j]  = (v ? rg : 0) * NCOL + (colok ? c : 0);
            rmask[j] = v ? 1.f : 0.f;
        }

        __syncthreads();

        // initial acquire: watermark covers 2 chunks -> prefetch t+1 always legal
        {
            const int tgt0 = (2 * CHUNK < TSTEPS) ? 2 * CHUNK : TSTEPS;
            while (__hip_atomic_load(&flags[0], __ATOMIC_ACQUIRE,
                                     __HIP_MEMORY_SCOPE_AGENT) < tgt0)
                __builtin_amdgcn_s_sleep(8);
        }
        // load h0[0] (masked) into current regs
        float hxc[7];
        {
            const float* hb = (const float*)zxrw;
#pragma unroll
            for (int j = 0; j < 7; ++j) hxc[j] = hb[roff[j]] * rmask[j];
        }

        for (int tc = 0; tc < TSTEPS; tc += CHUNK) {
            if (tc > 0) {
                int tgt = tc + 2 * CHUNK;
                if (tgt > TSTEPS) tgt = TSTEPS;
                while (__hip_atomic_load(&flags[0], __ATOMIC_ACQUIRE,
                                         __HIP_MEMORY_SCOPE_AGENT) < tgt)
                    __builtin_amdgcn_s_sleep(8);
            }

            for (int t = tc; t < tc + CHUNK; ++t) {
                const int pn = t & 1, pr_ = pn ^ 1;

                // issue NEXT step's h0 loads now; consumed next iteration
                float hxn[7];
                {
                    const int tn = (t + 1 < TSTEPS) ? (t + 1) : (TSTEPS - 1);
                    const float* hb = (const float*)((const char*)zxrw + (size_t)tn * 32000);
#pragma unroll
                    for (int j = 0; j < 7; ++j) hxn[j] = hb[roff[j]];
                }

                f2 uA[5], uB[5];
                {   // h-conv first (LDS + regs only)
                    float eh[7];
                    eh[0] = P1[pr_][w][1][c];
                    eh[6] = P1[pr_][w + 2][0][c];
#pragma unroll
                    for (int i = 0; i < 5; ++i) eh[i + 1] = h1[i];
                    conv5_s<true>(eh, Sh1a, Sh1b, uA, uB, B1a, B1b);
                }
                conv5_s<false>(hxc, Sx1a, Sx1b, uA, uB, B1a, B1b);   // x-conv on h0[t] (regs)

#pragma unroll
                for (int i = 0; i < 5; ++i)
                    h1[i] = gates_update(uA[i], uB[i], c1[i], maskf, sgkv);
                P1[pn][w + 1][0][c] = h1[0];
                P1[pn][w + 1][1][c] = h1[4];
                ldsbar();          // P1 parity barrier; hxn loads stay in flight

                // rotate prefetch into place; mask-mul doubles as the copy
#pragma unroll
                for (int j = 0; j < 7; ++j) hxc[j] = hxn[j] * rmask[j];
            }
        }

        if (colok) {
#pragma unroll
            for (int i = 0; i < 5; ++i)
                feat[(w * 5 + i) * NCOL + c] = h1[i];
        }
    }
}

// ============================================================================
// Single-CU scan (round-6 structure + LDS-only barriers) — fallback
// ============================================================================
__global__ __launch_bounds__(NTHR, 2) void convlstm_scan5(
        const float* __restrict__ zx,
        const float* __restrict__ w0g,
        const float* __restrict__ w1g, const float* __restrict__ b1g,
        float* __restrict__ feat) {
    __shared__ float P0[2][10][2][64];
    __shared__ float P1[2][10][2][64];

    const int tid = threadIdx.x;
    const int w = tid >> 6;
    const int c = tid & 63;
    const float maskf = (c < NCOL) ? 1.f : 0.f;
    const int cmin = (c < NCOL) ? c : (NCOL - 1);

    {
        float* p0 = &P0[0][0][0][0];
        float* p1 = &P1[0][0][0][0];
        for (int i = tid; i < 2 * 10 * 2 * 64; i += NTHR) { p0[i] = 0.f; p1[i] = 0.f; }
    }

    const float SA = -L2E;
    f2 Wh0a[9], Wh0b[9];
#pragma unroll
    for (int k = 0; k < 9; ++k) {
        Wh0a[k] = (f2){w0g[ 9 + k] * SA, w0g[27 + k] * SA};
        Wh0b[k] = (f2){w0g[45 + k] * SA, w0g[63 + k] * SGK};
    }
#pragma unroll
    for (int k = 0; k < 9; ++k)
        asm volatile("" : "+v"(Wh0a[k]), "+v"(Wh0b[k]));

    i64 Sx1a[9], Sx1b[9], Sh1a[9], Sh1b[9];
#pragma unroll
    for (int k = 0; k < 9; ++k) {
        Sx1a[k] = mk_sw(w1g[ 0 + k] * SA, w1g[18 + k] * SA);
        Sx1b[k] = mk_sw(w1g[36 + k] * SA, w1g[54 + k] * SGK);
        Sh1a[k] = mk_sw(w1g[ 9 + k] * SA, w1g[27 + k] * SA);
        Sh1b[k] = mk_sw(w1g[45 + k] * SA, w1g[63 + k] * SGK);
    }
    f2 B1a = (f2){b1g[0] * SA, b1g[1] * SA};
    f2 B1b = (f2){b1g[2] * SA, b1g[3] * SGK};
    asm volatile("" : "+v"(B1a), "+v"(B1b));

    float sgkv = SGK;
    asm volatile("" : "+v"(sgkv));

    float h0[5] = {0,0,0,0,0}, c0[5] = {0,0,0,0,0};
    float h1[5] = {0,0,0,0,0}, c1[5] = {0,0,0,0,0};

    const char* __restrict__ zb = (const char*)zx;
    int voff = ((w * 5) * NCOL + cmin) * 16;

    f2 zA[5], zB[5];
    {
        const char* p = zb + voff;
#pragma unroll
        for (int i = 0; i < 5; ++i) {
            const f4 z4 = *(const f4*)(p + i * 800);
            zA[i] = __builtin_shufflevector(z4, z4, 0, 1);
            zB[i] = __builtin_shufflevector(z4, z4, 2, 3);
        }
    }
    voff += 32000;

    __syncthreads();

    for (int t = 0; t < TSTEPS; ++t) {
        const int pn = t & 1, pr_ = pn ^ 1;
        {
            float e0[7];
            e0[0] = P0[pr_][w][1][c];
            e0[6] = P0[pr_][w + 2][0][c];
#pragma unroll
            for (int i = 0; i < 5; ++i) e0[i + 1] = h0[i];
            conv5_v(e0, Wh0a, Wh0b, zA, zB);
        }
#pragma unroll
        for (int i = 0; i < 5; ++i)
            h0[i] = gates_update(zA[i], zB[i], c0[i], maskf, sgkv);
        P0[pn][w + 1][0][c] = h0[0];
        P0[pn][w + 1][1][c] = h0[4];
        {
            const char* p = zb + voff;
#pragma unroll
            for (int i = 0; i < 5; ++i) {
                const f4 z4 = *(const f4*)(p + i * 800);
                zA[i] = __builtin_shufflevector(z4, z4, 0, 1);
                zB[i] = __builtin_shufflevector(z4, z4, 2, 3);
            }
            if (t + 2 < TSTEPS) voff += 32000;
        }
        ldsbar();
        f2 uA[5], uB[5];
        {
            float ex[7];
            ex[0] = P0[pn][w][1][c];
            ex[6] = P0[pn][w + 2][0][c];
#pragma unroll
            for (int i = 0; i < 5; ++i) ex[i + 1] = h0[i];
            conv5_s<true>(ex, Sx1a, Sx1b, uA, uB, B1a, B1b);
        }
        {
            float eh[7];
            eh[0] = P1[pr_][w][1][c];
            eh[6] = P1[pr_][w + 2][0][c];
#pragma unroll
            for (int i = 0; i < 5; ++i) eh[i + 1] = h1[i];
            conv5_s<false>(eh, Sh1a, Sh1b, uA, uB, B1a, B1b);
        }
#pragma unroll
        for (int i = 0; i < 5; ++i)
            h1[i] = gates_update(uA[i], uB[i], c1[i], maskf, sgkv);
        P1[pn][w + 1][0][c] = h1[0];
        P1[pn][w + 1][1][c] = h1[4];
        ldsbar();
    }

    if (c < NCOL) {
#pragma unroll
        for (int i = 0; i < 5; ++i)
            feat[(w * 5 + i) * NCOL + c] = h1[i];
    }
}

// ============================================================================
// Fallback monolithic scan (round-1, known-correct; used only if ws too small)
// ============================================================================
#define PW 52
#define PH 42
__device__ __forceinline__ void cell_update(const float* __restrict__ xf,
                                            const float* __restrict__ hf,
                                            const float (&wr)[72], const float (&br)[4],
                                            const int (&pidx)[4],
                                            float (&cst)[4], float (&hn)[4]) {
#pragma unroll
    for (int q = 0; q < 4; ++q) {
        const int p = pidx[q];
        float z0 = br[0], z1 = br[1], z2 = br[2], z3 = br[3];
#pragma unroll
        for (int ky = 0; ky < 3; ++ky)
#pragma unroll
            for (int kx = 0; kx < 3; ++kx) {
                const int off = (ky - 1) * PW + (kx - 1);
                const float xval = xf[p + off];
                const float hval = hf[p + off];
                const int wi = ky * 3 + kx;
                z0 += wr[ 0 + wi] * xval + wr[ 9 + wi] * hval;
                z1 += wr[18 + wi] * xval + wr[27 + wi] * hval;
                z2 += wr[36 + wi] * xval + wr[45 + wi] * hval;
                z3 += wr[54 + wi] * xval + wr[63 + wi] * hval;
            }
        const float ig = sigm(z0), fg = sigm(z1), og = sigm(z2), gg = tanh_f(z3);
        const float cn = fg * cst[q] + ig * gg;
        cst[q] = cn;
        hn[q]  = og * tanh_f(cn);
    }
}

__global__ __launch_bounds__(NTHR, 2) void convlstm_scan(
    const float* __restrict__ s,
    const float* __restrict__ w0g, const float* __restrict__ b0g,
    const float* __restrict__ w1g, const float* __restrict__ b1g,
    float* __restrict__ feat) {
    __shared__ float xb[PH * PW];
    __shared__ float h0[PH * PW];
    __shared__ float h1[PH * PW];
    const int tid = threadIdx.x;
    for (int i = tid; i < PH * PW; i += NTHR) { xb[i] = 0.f; h0[i] = 0.f; h1[i] = 0.f; }
    float w0r[72], w1r[72], b0r[4], b1r[4];
#pragma unroll
    for (int i = 0; i < 72; ++i) w0r[i] = w0g[i];
#pragma unroll
    for (int i = 0; i < 72; ++i) w1r[i] = w1g[i];
#pragma unroll
    for (int i = 0; i < 4; ++i) { b0r[i] = b0g[i]; b1r[i] = b1g[i]; }
    int pidx[4]; bool cv[4];
#pragma unroll
    for (int q = 0; q < 4; ++q) {
        int cell = tid + q * NTHR;
        cv[q] = (cell < NCELL);
        if (!cv[q]) cell = 0;
        const int r = cell / NCOL, cc = cell % NCOL;
        pidx[q] = (r + 1) * PW + (cc + 1);
    }
    int xjj[4], xpp[4]; bool xv[4];
#pragma unroll
    for (int k = 0; k < 4; ++k) {
        int j = tid + k * NTHR;
        xv[k] = (j < INLEN);
        if (!xv[k]) j = 0;
        xjj[k] = j;
        const int r = j / NCOL, cc = j % NCOL;
        xpp[k] = (r + 1) * PW + (cc + 1);
    }
    float c0r[4] = {0,0,0,0}, c1r[4] = {0,0,0,0};
    float xr[4];
#pragma unroll
    for (int k = 0; k < 4; ++k) xr[k] = xv[k] ? s[xjj[k]] : 0.f;
    __syncthreads();
    for (int t = 0; t < TSTEPS; ++t) {
#pragma unroll
        for (int k = 0; k < 4; ++k)
            if (xv[k]) xb[xpp[k]] = xr[k];
        {
            const size_t bofs = (size_t)(t + 1 < TSTEPS ? t + 1 : t) * INLEN;
#pragma unroll
            for (int k = 0; k < 4; ++k) xr[k] = xv[k] ? s[bofs + xjj[k]] : 0.f;
        }
        __syncthreads();
        float hn0[4];
        cell_update(xb, h0, w0r, b0r, pidx, c0r, hn0);
        __syncthreads();
#pragma unroll
        for (int q = 0; q < 4; ++q)
            if (cv[q]) h0[pidx[q]] = hn0[q];
        __syncthreads();
        float hn1[4];
        cell_update(h0, h1, w1r, b1r, pidx, c1r, hn1);
        __syncthreads();
#pragma unroll
        for (int q = 0; q < 4; ++q)
            if (cv[q]) h1[pidx[q]] = hn1[q];
    }
#pragma unroll
    for (int q = 0; q < 4; ++q)
        if (cv[q]) feat[tid + q * NTHR] = h1[pidx[q]];
}

// ============================================================================
// FC epilogue
// ============================================================================
__global__ __launch_bounds__(256) void fc_kernel(const float* __restrict__ feat,
                                                 const float* __restrict__ w,
                                                 const float* __restrict__ b,
                                                 float* __restrict__ out) {
    const int j   = blockIdx.x;
    const int tid = threadIdx.x;
    const float* __restrict__ wr = w + (size_t)j * NCELL;
    float acc = 0.f;
    for (int k = tid; k < NCELL; k += 256) {
        float f = feat[k];
        f = (f > 0.f) ? f : 0.01f * f;
        acc += f * wr[k];
    }
#pragma unroll
    for (int off = 32; off > 0; off >>= 1) acc += __shfl_down(acc, off, 64);
    __shared__ float red[4];
    const int wv = tid >> 6, ln = tid & 63;
    if (ln == 0) red[wv] = acc;
    __syncthreads();
    if (tid == 0) {
        const float a = red[0] + red[1] + red[2] + red[3] + b[j];
        out[j] = fastrcp(1.0f + __expf(-a));
    }
}

extern "C" void kernel_launch(void* const* d_in, const int* in_sizes, int n_in,
                              void* d_out, int out_size, void* d_ws, size_t ws_size,
                              hipStream_t stream) {
    const float* s   = (const float*)d_in[0];
    const float* w0  = (const float*)d_in[1];
    const float* b0  = (const float*)d_in[2];
    const float* w1  = (const float*)d_in[3];
    const float* b1  = (const float*)d_in[4];
    const float* fcw = (const float*)d_in[5];
    const float* fcb = (const float*)d_in[6];
    float* out  = (float*)d_out;
    float* feat = (float*)d_ws;   // 2000 floats

    const size_t zx_bytes = (size_t)TSTEPS * NCELL * 4 * sizeof(float);
    if (ws_size >= zx_bytes + ZX_OFF) {
        // 2-CU chunked-pipeline path with consumer prefetch + LDS-only barriers
        int*   flags = (int*)((char*)d_ws + FLAGS_OFF);
        float* zx    = (float*)((char*)d_ws + ZX_OFF);
        zx_prepass4<<<TSTEPS, 256, 0, stream>>>(s, w0, b0, zx, flags);
        convlstm_pipe4<<<2, NTHR, 0, stream>>>(zx, w0, w1, b1, feat, flags);
    } else if (ws_size >= zx_bytes + 8192) {
        // single-CU round-6 path
        int*   flags = (int*)((char*)d_ws + 4096);   // scratch (rewritten by feat later)
        float* zx    = (float*)((char*)d_ws + 8192);
        zx_prepass4<<<TSTEPS, 256, 0, stream>>>(s, w0, b0, zx, flags);
        convlstm_scan5<<<1, NTHR, 0, stream>>>(zx, w0, w1, b1, feat);
    } else {
        convlstm_scan<<<1, NTHR, 0, stream>>>(s, w0, b0, w1, b1, feat);
    }
    fc_kernel<<<NCELL, 256, 0, stream>>>(feat, fcw, fcb, out);
}